// Round 1
// baseline (94.408 us; speedup 1.0000x reference)
//
#include <hip/hip_runtime.h>
#include <hip/hip_bf16.h>

// SetCriterion: B=256 independent optimal assignments (JV) on 300x16 NLL cost
// matrices + weighted BCE on [256,32]. Output: ONE FP32 SCALAR =
//   0.1 * mean(assigned costs over 256*16) + mean(TRIPLET_W * bce over 256*32)
//
// R8: 512-thread blocks (8 waves). Raw logit slab (28.8 KB/batch) is staged
// into LDS with coalesced float4 loads; the per-thread nll scratch (scr) is
// ELIMINATED -- the gather nll[g] = lse - x[g] reads the staged slab directly
// at odd per-lane strides (9/13/3 words -> bank-conflict-free). Each thread
// now computes exactly ONE softmax row (R7's wave-0 did two, and wave 0 is
// also the JV critical path). After the barrier: wave 0 runs the validated
// register-resident JV alone, wave 1 computes BCE concurrently, waves 2-7
// retire. __expf/__logf hardware intrinsics (~1e-6 rel err vs 2.1e-2 thresh).

#define BT 512
#define NW 8
#define NQ 300
#define NG 16
#define NT 5            // wave-0 column slots per lane (5*64 = 320 >= 300)
#define SH 2700         // staged pred_head floats  (300*9)
#define SR 3900         // staged pred_rel  floats  (300*13)
#define ST 900          // staged pred_tail floats  (300*3, padded: odd stride)

__device__ const float d_tw[32] = {
    1.17236407f, 1.0166286f,  1.19620973f, 0.5544405f,  0.63531401f, 0.51258428f,
    1.08866652f, 1.15795989f, 1.07389395f, 0.98728399f, 1.12754142f, 1.05953744f,
    1.16945323f, 1.15512349f, 1.02097204f, 1.15795989f, 1.07147279f, 0.50627649f,
    1.07147279f, 0.61697221f, 1.16367678f, 1.0231585f,  1.18416106f, 1.04329092f,
    1.10645159f, 1.18416106f, 1.15795989f, 1.16367678f, 0.73949534f, 0.78760821f,
    1.08617476f, 1.00805777f};

// wave64 min-reduce via DPP; returns min as a wave-uniform value (validated R6).
__device__ __forceinline__ float wave_min_bcast(float x) {
    int t;
    t = __builtin_amdgcn_update_dpp(__float_as_int(x), __float_as_int(x), 0x111, 0xF, 0xF, false);
    x = fminf(x, __int_as_float(t));   // row_shr:1
    t = __builtin_amdgcn_update_dpp(__float_as_int(x), __float_as_int(x), 0x112, 0xF, 0xF, false);
    x = fminf(x, __int_as_float(t));   // row_shr:2
    t = __builtin_amdgcn_update_dpp(__float_as_int(x), __float_as_int(x), 0x114, 0xF, 0xF, false);
    x = fminf(x, __int_as_float(t));   // row_shr:4
    t = __builtin_amdgcn_update_dpp(__float_as_int(x), __float_as_int(x), 0x118, 0xF, 0xF, false);
    x = fminf(x, __int_as_float(t));   // row_shr:8
    t = __builtin_amdgcn_update_dpp(__float_as_int(x), __float_as_int(x), 0x142, 0xF, 0xF, false);
    x = fminf(x, __int_as_float(t));   // row_bcast:15
    t = __builtin_amdgcn_update_dpp(__float_as_int(x), __float_as_int(x), 0x143, 0xF, 0xF, false);
    x = fminf(x, __int_as_float(t));   // row_bcast:31 -> lane 63 = global min
    return __int_as_float(__builtin_amdgcn_readlane(__float_as_int(x), 63));
}

// 8 waves per block, one block per batch
__global__ __launch_bounds__(BT) void SetCriterion_14482629722575_kernel(
    const float* __restrict__ ph, const float* __restrict__ pr,
    const float* __restrict__ pt, const float* __restrict__ ivt,
    const int* __restrict__ iid, const int* __restrict__ vid,
    const int* __restrict__ tid_, const int* __restrict__ trip,
    float* __restrict__ out)
{
    const int b    = blockIdx.x;
    const int tid  = threadIdx.x;
    const int wave = tid >> 6;
    const int lane = tid & 63;
    const float FINF = 3.0e38f;

    __shared__ __align__(16) float stage[SH + SR + ST];  // 30000 B raw logits
    __shared__ float cost[NG * NQ];                      // 19200 B
    __shared__ float pmin[NW][NG];                       // per-wave row-min partials
    __shared__ int   pjm[NW][NG];                        //   + argmin columns (1-based)
    __shared__ int   sgi[NG], sgv[NG], sgt[NG];

    float* sh_ = stage;
    float* sr_ = stage + SH;
    float* st_ = stage + SH + SR;

    // ---- coalesced global -> LDS staging (float4; slab bases are 16B-aligned:
    //      b*10800, b*15600, b*2400 are all multiples of 16) ----
    {
        const float4* s4 = (const float4*)(ph + (size_t)b * SH);
        float4* d4 = (float4*)sh_;
        for (int i = tid; i < SH / 4; i += BT) d4[i] = s4[i];
    }
    {
        const float4* s4 = (const float4*)(pr + (size_t)b * SR);
        float4* d4 = (float4*)sr_;
        for (int i = tid; i < SR / 4; i += BT) d4[i] = s4[i];
    }
    {
        const float2* s2 = (const float2*)(pt + (size_t)b * (NQ * 2));
        for (int i = tid; i < NQ; i += BT) {
            const float2 v = s2[i];
            st_[i * 3]     = v.x;          // padded stride-3 layout: odd stride
            st_[i * 3 + 1] = v.y;          //  -> conflict-free gather later
        }
    }
    if (tid < NG) {
        sgi[tid] = iid[b * NG + tid];
        sgv[tid] = vid[b * NG + tid];
        sgt[tid] = tid_[b * NG + tid];
    }
    __syncthreads();

    int gi[NG], gv[NG], gc[NG];
    #pragma unroll
    for (int i = 0; i < NG; i++) { gi[i] = sgi[i]; gv[i] = sgv[i]; gc[i] = sgt[i]; }

    float rmin[NG]; int rjm[NG];
    #pragma unroll
    for (int i = 0; i < NG; i++) { rmin[i] = FINF; rjm[i] = 0; }

    // ---- phase 1: one softmax row per thread, gather from staged slab ----
    if (tid < NQ) {
        const int q = tid;
        float lh, lr, lt;
        {
            const float* x = sh_ + q * 9;
            float r[9];
            #pragma unroll
            for (int c = 0; c < 9; c++) r[c] = x[c];
            float m = r[0];
            #pragma unroll
            for (int c = 1; c < 9; c++) m = fmaxf(m, r[c]);
            float sE = 0.f;
            #pragma unroll
            for (int c = 0; c < 9; c++) sE += __expf(r[c] - m);
            lh = m + __logf(sE);
        }
        {
            const float* x = sr_ + q * 13;
            float r[13];
            #pragma unroll
            for (int c = 0; c < 13; c++) r[c] = x[c];
            float m = r[0];
            #pragma unroll
            for (int c = 1; c < 13; c++) m = fmaxf(m, r[c]);
            float sE = 0.f;
            #pragma unroll
            for (int c = 0; c < 13; c++) sE += __expf(r[c] - m);
            lr = m + __logf(sE);
        }
        {
            const float r0 = st_[q * 3], r1 = st_[q * 3 + 1];
            const float m = fmaxf(r0, r1);
            lt = m + __logf(__expf(r0 - m) + __expf(r1 - m));
        }
        const float lsum = lh + lr + lt;
        // gathers: per-lane word strides 9/13/3 (all odd-ish, gcd<...,32> bank-safe)
        #pragma unroll
        for (int i = 0; i < NG; i++) {
            const float c = lsum -
                (sh_[q * 9 + gi[i]] + sr_[q * 13 + gv[i]] + st_[q * 3 + gc[i]]);
            cost[i * NQ + q] = c;
            rmin[i] = c; rjm[i] = q + 1;
        }
    }

    // per-wave row-min partials -> LDS (all lanes execute the DPP reduce;
    // inactive / q>=NQ lanes carry FINF)
    #pragma unroll
    for (int i = 0; i < NG; i++) {
        const float m = wave_min_bcast(rmin[i]);
        const unsigned long long msk = __ballot(rmin[i] == m);
        const int l0 = (int)__ffsll(msk) - 1;
        const int jm = __builtin_amdgcn_readlane(rjm[i], l0);
        if (lane == 0) { pmin[wave][i] = m; pjm[wave][i] = jm; }
    }
    __syncthreads();   // cost/pmin stable after this

    // ---- wave 1: weighted BCE, concurrent with wave 0's JV ----
    if (wave == 1) {
        float bs = 0.f;
        if (lane < 32) {
            const float x  = ivt[b * 32 + lane];
            const float tt = (float)trip[b * 32 + lane];
            const float e  = __expf(-fabsf(x));
            bs = d_tw[lane] * (fmaxf(x, 0.f) - x * tt + __logf(1.f + e));
        }
        #pragma unroll
        for (int off = 32; off >= 1; off >>= 1) bs += __shfl_xor(bs, off);
        if (lane == 0) atomicAdd(out, bs / 8192.0f);
        return;
    }
    if (wave != 0) return;

    // ---- wave 0: combine row-min partials (wave-uniform LDS broadcast reads) ----
    float um[NG]; int jm_[NG];
    #pragma unroll
    for (int i = 0; i < NG; i++) {
        float m = pmin[0][i]; int jm = pjm[0][i];
        #pragma unroll
        for (int w = 1; w < NW; w++) {
            const float mw = pmin[w][i]; const int jw = pjm[w][i];
            if (mw < m) { m = mw; jm = jw; }
        }
        um[i] = m; jm_[i] = jm;
    }

    // ---- JV state: lane owns columns j = t*64+lane+1 ----
    float v_[NT], minv_[NT];
    int   way_[NT], par_[NT];
    bool  valid[NT];
    #pragma unroll
    for (int t = 0; t < NT; t++) {
        valid[t] = (t * 64 + lane + 1 <= NQ);
        v_[t] = 0.f; par_[t] = 0; way_[t] = 0; minv_[t] = FINF;
    }

    // ---- greedy seeding: conflicts via scalar compares on uniform jm values ----
    int pending = 0;
    #pragma unroll
    for (int i = 1; i < NG; i++) {
        bool conf = false;
        #pragma unroll
        for (int k = 0; k < NG; k++)
            if (k < i && jm_[k] == jm_[i]) conf = true;
        if (conf) pending |= 1 << i;        // bit i <-> row i+1
    }
    #pragma unroll
    for (int i = 0; i < NG; i++) {
        if (!((pending >> i) & 1)) {
            const int jm = jm_[i];
            const int slot = (jm - 1) >> 6, owner = (jm - 1) & 63;
            #pragma unroll
            for (int t = 0; t < NT; t++)
                if (slot == t && lane == owner) par_[t] = i + 1;
        }
    }

    // ---- augment each conflicted row (usually 0-2 per batch) ----
    while (pending) {
        const int r = __ffs(pending);       // row 1..16
        pending &= pending - 1;
        #pragma unroll
        for (int t = 0; t < NT; t++) minv_[t] = FINF;
        unsigned usedbits = 0;
        float u0 = 0.f;
        #pragma unroll
        for (int i = 0; i < NG; i++) if (r == i + 1) u0 = um[i];
        int i0 = r, j0 = 0, guard = 0;

        while (true) {
            if (j0 && ((j0 - 1) & 63) == lane) usedbits |= 1u << ((j0 - 1) >> 6);

            const int rowbase = (i0 - 1) * NQ;
            float raw[NT];
            #pragma unroll
            for (int t = 0; t < NT; t++) {
                const int j = t * 64 + lane + 1;
                raw[t] = (valid[t] ? cost[rowbase + j - 1] : FINF) - v_[t];
            }

            float lmin = FINF;
            int   lmeta = 0x7FFFFFFF;
            #pragma unroll
            for (int t = 0; t < NT; t++) {
                if (valid[t] && !((usedbits >> t) & 1u)) {
                    const float cur = raw[t] - u0;
                    if (cur < minv_[t]) { minv_[t] = cur; way_[t] = j0; }
                    if (minv_[t] < lmin) {
                        lmin = minv_[t];
                        lmeta = ((t * 64 + lane + 1) << 5) | par_[t];
                    }
                }
            }
            const float delta = wave_min_bcast(lmin);
            const unsigned long long msk = __ballot(lmin == delta);
            const int l0 = (int)__ffsll(msk) - 1;
            const int meta = __builtin_amdgcn_readlane(lmeta, l0);
            const int j1 = meta >> 5, i1 = meta & 31;

            #pragma unroll
            for (int t = 0; t < NT; t++) {
                if ((usedbits >> t) & 1u) v_[t] -= delta;
                else                      minv_[t] -= delta;
            }

            if (i1 == 0) { j0 = j1; break; }   // free column -> augment

            // u[i1] via complementary slackness: C[i1][j1] - v[j1]
            {
                const int slot = (j1 - 1) >> 6, owner = (j1 - 1) & 63;
                float vsel = v_[0];
                #pragma unroll
                for (int t = 1; t < NT; t++) if (slot == t) vsel = v_[t];
                const float vj1 = __int_as_float(
                    __builtin_amdgcn_readlane(__float_as_int(vsel), owner));
                u0 = cost[(i1 - 1) * NQ + (j1 - 1)] - vj1;
            }
            j0 = j1; i0 = i1;
            if (++guard > 40) break;           // safety; tree <= 17 columns
        }

        // backtrack the way-chain (wave-uniform indices -> readlane)
        int jj = j0;
        while (jj) {
            const int slot = (jj - 1) >> 6, owner = (jj - 1) & 63;
            int wsel = way_[0];
            #pragma unroll
            for (int t = 1; t < NT; t++) if (slot == t) wsel = way_[t];
            const int wj = __builtin_amdgcn_readlane(wsel, owner);
            int pj;
            if (wj == 0) pj = r;
            else {
                const int s2 = (wj - 1) >> 6, o2 = (wj - 1) & 63;
                int psel = par_[0];
                #pragma unroll
                for (int t = 1; t < NT; t++) if (s2 == t) psel = par_[t];
                pj = __builtin_amdgcn_readlane(psel, o2);
            }
            #pragma unroll
            for (int t = 0; t < NT; t++)
                if (slot == t && ((jj - 1) & 63) == lane) par_[t] = pj;
            jj = wj;
        }
    }

    // ---- assigned-cost sum (exactly NG matched columns) ----
    float s = 0.f;
    #pragma unroll
    for (int t = 0; t < NT; t++) {
        const int j = t * 64 + lane + 1;
        if (valid[t] && par_[t] > 0)
            s += cost[(par_[t] - 1) * NQ + (j - 1)];
    }
    #pragma unroll
    for (int off = 32; off >= 1; off >>= 1) s += __shfl_xor(s, off);

    if (lane == 0)
        atomicAdd(out, 0.1f * (s / 4096.0f));
}

extern "C" void kernel_launch(void* const* d_in, const int* in_sizes, int n_in,
                              void* d_out, int out_size, void* d_ws, size_t ws_size,
                              hipStream_t stream) {
    (void)in_sizes; (void)n_in; (void)d_ws; (void)ws_size; (void)out_size;

    const float* pred_head    = (const float*)d_in[0];
    const float* pred_rel     = (const float*)d_in[1];
    const float* pred_tail    = (const float*)d_in[2];
    const float* IVT          = (const float*)d_in[3];
    const int*   instrumentId = (const int*)d_in[4];
    const int*   verbId       = (const int*)d_in[5];
    const int*   targetId     = (const int*)d_in[6];
    // d_in[7..9] = instrument, verb, target (unused by the reference loss)
    const int*   triplet      = (const int*)d_in[10];
    // d_in[11] = mask (all-ones in setup; all 16 gt slots valid)

    hipMemsetAsync(d_out, 0, 4, stream);   // zero the fp32 accumulator each call

    SetCriterion_14482629722575_kernel<<<256, BT, 0, stream>>>(
        pred_head, pred_rel, pred_tail, IVT,
        instrumentId, verbId, targetId, triplet, (float*)d_out);
}

// Round 2
// 91.926 us; speedup vs baseline: 1.0270x; 1.0270x over previous
//
#include <hip/hip_runtime.h>

// SetCriterion: B=256 independent optimal assignments (JV) on 300x16 NLL cost
// matrices + weighted BCE on [256,32]. Output: ONE FP32 SCALAR =
//   0.1 * mean(assigned costs over 256*16) + mean(TRIPLET_W * bce over 256*32)
//
// R9: 320-thread blocks (5 waves, all productive). PER-WAVE staging: each wave
// cooperatively loads ONLY its own 64 rows' logits into LDS (coalesced float4)
// and orders the ds_write->ds_read RAW with a wave-local s_waitcnt lgkmcnt(0)
// -- NO block barrier before compute (phase 1 is row-local: thread q gathers
// only from row q). Back to R7's single-__syncthreads structure but with R8's
// coalesced loads + one-softmax-row-per-thread. gt ids come from block-uniform
// scalar loads (s_load) instead of an LDS round-trip. Wave 1's BCE inputs are
// prefetched at kernel start so HBM latency hides under phase 1 + barrier.
// After the barrier: wave 0 runs the validated register-resident JV alone,
// wave 1 computes BCE concurrently, waves 2-4 retire.

#define BT 320
#define NW 5
#define NQ 300
#define NG 16
#define NT 5            // wave-0 column slots per lane (5*64 = 320 >= 300)
#define SH 2700         // staged pred_head floats  (300*9)
#define SR 3900         // staged pred_rel  floats  (300*13)
#define ST 900          // staged pred_tail floats  (300*3, padded: odd stride)

__device__ const float d_tw[32] = {
    1.17236407f, 1.0166286f,  1.19620973f, 0.5544405f,  0.63531401f, 0.51258428f,
    1.08866652f, 1.15795989f, 1.07389395f, 0.98728399f, 1.12754142f, 1.05953744f,
    1.16945323f, 1.15512349f, 1.02097204f, 1.15795989f, 1.07147279f, 0.50627649f,
    1.07147279f, 0.61697221f, 1.16367678f, 1.0231585f,  1.18416106f, 1.04329092f,
    1.10645159f, 1.18416106f, 1.15795989f, 1.16367678f, 0.73949534f, 0.78760821f,
    1.08617476f, 1.00805777f};

// wave64 min-reduce via DPP; returns min as a wave-uniform value (validated R6).
__device__ __forceinline__ float wave_min_bcast(float x) {
    int t;
    t = __builtin_amdgcn_update_dpp(__float_as_int(x), __float_as_int(x), 0x111, 0xF, 0xF, false);
    x = fminf(x, __int_as_float(t));   // row_shr:1
    t = __builtin_amdgcn_update_dpp(__float_as_int(x), __float_as_int(x), 0x112, 0xF, 0xF, false);
    x = fminf(x, __int_as_float(t));   // row_shr:2
    t = __builtin_amdgcn_update_dpp(__float_as_int(x), __float_as_int(x), 0x114, 0xF, 0xF, false);
    x = fminf(x, __int_as_float(t));   // row_shr:4
    t = __builtin_amdgcn_update_dpp(__float_as_int(x), __float_as_int(x), 0x118, 0xF, 0xF, false);
    x = fminf(x, __int_as_float(t));   // row_shr:8
    t = __builtin_amdgcn_update_dpp(__float_as_int(x), __float_as_int(x), 0x142, 0xF, 0xF, false);
    x = fminf(x, __int_as_float(t));   // row_bcast:15
    t = __builtin_amdgcn_update_dpp(__float_as_int(x), __float_as_int(x), 0x143, 0xF, 0xF, false);
    x = fminf(x, __int_as_float(t));   // row_bcast:31 -> lane 63 = global min
    return __int_as_float(__builtin_amdgcn_readlane(__float_as_int(x), 63));
}

// 5 waves per block, one block per batch
__global__ __launch_bounds__(BT) void SetCriterion_14482629722575_kernel(
    const float* __restrict__ ph, const float* __restrict__ pr,
    const float* __restrict__ pt, const float* __restrict__ ivt,
    const int* __restrict__ iid, const int* __restrict__ vid,
    const int* __restrict__ tid_, const int* __restrict__ trip,
    float* __restrict__ out)
{
    const int b    = blockIdx.x;
    const int tid  = threadIdx.x;
    const int wave = tid >> 6;
    const int lane = tid & 63;
    const float FINF = 3.0e38f;

    __shared__ __align__(16) float stage[SH + SR + ST];  // 30000 B raw logits
    __shared__ float cost[NG * NQ];                      // 19200 B
    __shared__ float pmin[NW][NG];                       // per-wave row-min partials
    __shared__ int   pjm[NW][NG];                        //   + argmin columns (1-based)

    float* sh_ = stage;
    float* sr_ = stage + SH;
    float* st_ = stage + SH + SR;

    // ---- wave 1: prefetch BCE inputs (consumed after the barrier; latency
    //      hides under staging + phase 1) ----
    float bce_x = 0.f, bce_t = 0.f;
    if (wave == 1 && lane < 32) {
        bce_x = ivt[b * 32 + lane];
        bce_t = (float)trip[b * 32 + lane];
    }

    // ---- gt ids: block-uniform addresses -> scalar loads, no LDS round-trip ----
    int gi[NG], gv[NG], gc[NG];
    #pragma unroll
    for (int i = 0; i < NG; i++) {
        gi[i] = iid[b * NG + i];
        gv[i] = vid[b * NG + i];
        gc[i] = tid_[b * NG + i];
    }

    // ---- PER-WAVE staging: wave w loads ONLY its own rows [64w, 64w+64)
    //      (coalesced float4; slab bases b*10800/b*15600/b*2400 are 16B-aligned).
    //      Ranges clamped so wave 4 neither reads past the batch slab nor
    //      writes past its LDS region. ----
    {
        const float4* s4 = (const float4*)(ph + (size_t)b * SH);
        float4* d4 = (float4*)sh_;
        const int hi = (144 * (wave + 1) < SH / 4) ? 144 * (wave + 1) : SH / 4;
        for (int k = 144 * wave + lane; k < hi; k += 64) d4[k] = s4[k];
    }
    {
        const float4* s4 = (const float4*)(pr + (size_t)b * SR);
        float4* d4 = (float4*)sr_;
        const int hi = (208 * (wave + 1) < SR / 4) ? 208 * (wave + 1) : SR / 4;
        for (int k = 208 * wave + lane; k < hi; k += 64) d4[k] = s4[k];
    }
    {
        // pred_tail: 2 floats/row -> padded stride-3 LDS layout (odd stride).
        // float4 k covers rows 2k, 2k+1. Wave w owns float4s [32w, 32w+32).
        const float4* s4 = (const float4*)(pt + (size_t)b * (NQ * 2));
        const int hi = (32 * (wave + 1) < 150) ? 32 * (wave + 1) : 150;
        const int k = 32 * wave + lane;
        if (lane < 32 && k < hi) {
            const float4 v = s4[k];
            const int r0 = 2 * k, r1 = 2 * k + 1;
            st_[r0 * 3]     = v.x;
            st_[r0 * 3 + 1] = v.y;
            st_[r1 * 3]     = v.z;
            st_[r1 * 3 + 1] = v.w;
        }
    }
    // wave-local RAW ordering: all ds_writes above complete before the ds_reads
    // below (same wave, lockstep; DS ops tracked by lgkmcnt). No block barrier.
    asm volatile("s_waitcnt lgkmcnt(0)" ::: "memory");

    float rmin[NG]; int rjm[NG];
    #pragma unroll
    for (int i = 0; i < NG; i++) { rmin[i] = FINF; rjm[i] = 0; }

    // ---- phase 1: one softmax row per thread, gather from own staged row ----
    if (tid < NQ) {
        const int q = tid;
        float lh, lr, lt;
        {
            const float* x = sh_ + q * 9;
            float r[9];
            #pragma unroll
            for (int c = 0; c < 9; c++) r[c] = x[c];
            float m = r[0];
            #pragma unroll
            for (int c = 1; c < 9; c++) m = fmaxf(m, r[c]);
            float sE = 0.f;
            #pragma unroll
            for (int c = 0; c < 9; c++) sE += __expf(r[c] - m);
            lh = m + __logf(sE);
        }
        {
            const float* x = sr_ + q * 13;
            float r[13];
            #pragma unroll
            for (int c = 0; c < 13; c++) r[c] = x[c];
            float m = r[0];
            #pragma unroll
            for (int c = 1; c < 13; c++) m = fmaxf(m, r[c]);
            float sE = 0.f;
            #pragma unroll
            for (int c = 0; c < 13; c++) sE += __expf(r[c] - m);
            lr = m + __logf(sE);
        }
        {
            const float r0 = st_[q * 3], r1 = st_[q * 3 + 1];
            const float m = fmaxf(r0, r1);
            lt = m + __logf(__expf(r0 - m) + __expf(r1 - m));
        }
        const float lsum = lh + lr + lt;
        // gathers: per-lane word strides 9/13/3 (odd -> bank-conflict-free)
        #pragma unroll
        for (int i = 0; i < NG; i++) {
            const float c = lsum -
                (sh_[q * 9 + gi[i]] + sr_[q * 13 + gv[i]] + st_[q * 3 + gc[i]]);
            cost[i * NQ + q] = c;
            rmin[i] = c; rjm[i] = q + 1;
        }
    }

    // per-wave row-min partials -> LDS (all lanes execute the DPP reduce;
    // inactive / q>=NQ lanes carry FINF)
    #pragma unroll
    for (int i = 0; i < NG; i++) {
        const float m = wave_min_bcast(rmin[i]);
        const unsigned long long msk = __ballot(rmin[i] == m);
        const int l0 = (int)__ffsll(msk) - 1;
        const int jm = __builtin_amdgcn_readlane(rjm[i], l0);
        if (lane == 0) { pmin[wave][i] = m; pjm[wave][i] = jm; }
    }
    __syncthreads();   // the ONLY block-wide barrier; cost/pmin stable after this

    // ---- wave 1: weighted BCE, concurrent with wave 0's JV ----
    if (wave == 1) {
        float bs = 0.f;
        if (lane < 32) {
            const float x = bce_x;
            const float e = __expf(-fabsf(x));
            bs = d_tw[lane] * (fmaxf(x, 0.f) - x * bce_t + __logf(1.f + e));
        }
        #pragma unroll
        for (int off = 32; off >= 1; off >>= 1) bs += __shfl_xor(bs, off);
        if (lane == 0) atomicAdd(out, bs / 8192.0f);
        return;
    }
    if (wave != 0) return;

    // ---- wave 0: combine row-min partials (wave-uniform LDS broadcast reads) ----
    float um[NG]; int jm_[NG];
    #pragma unroll
    for (int i = 0; i < NG; i++) {
        float m = pmin[0][i]; int jm = pjm[0][i];
        #pragma unroll
        for (int w = 1; w < NW; w++) {
            const float mw = pmin[w][i]; const int jw = pjm[w][i];
            if (mw < m) { m = mw; jm = jw; }
        }
        um[i] = m; jm_[i] = jm;
    }

    // ---- JV state: lane owns columns j = t*64+lane+1 ----
    float v_[NT], minv_[NT];
    int   way_[NT], par_[NT];
    bool  valid[NT];
    #pragma unroll
    for (int t = 0; t < NT; t++) {
        valid[t] = (t * 64 + lane + 1 <= NQ);
        v_[t] = 0.f; par_[t] = 0; way_[t] = 0; minv_[t] = FINF;
    }

    // ---- greedy seeding: conflicts via scalar compares on uniform jm values ----
    int pending = 0;
    #pragma unroll
    for (int i = 1; i < NG; i++) {
        bool conf = false;
        #pragma unroll
        for (int k = 0; k < NG; k++)
            if (k < i && jm_[k] == jm_[i]) conf = true;
        if (conf) pending |= 1 << i;        // bit i <-> row i+1
    }
    #pragma unroll
    for (int i = 0; i < NG; i++) {
        if (!((pending >> i) & 1)) {
            const int jm = jm_[i];
            const int slot = (jm - 1) >> 6, owner = (jm - 1) & 63;
            #pragma unroll
            for (int t = 0; t < NT; t++)
                if (slot == t && lane == owner) par_[t] = i + 1;
        }
    }

    // ---- augment each conflicted row (usually 0-2 per batch) ----
    while (pending) {
        const int r = __ffs(pending);       // row 1..16
        pending &= pending - 1;
        #pragma unroll
        for (int t = 0; t < NT; t++) minv_[t] = FINF;
        unsigned usedbits = 0;
        float u0 = 0.f;
        #pragma unroll
        for (int i = 0; i < NG; i++) if (r == i + 1) u0 = um[i];
        int i0 = r, j0 = 0, guard = 0;

        while (true) {
            if (j0 && ((j0 - 1) & 63) == lane) usedbits |= 1u << ((j0 - 1) >> 6);

            const int rowbase = (i0 - 1) * NQ;
            float raw[NT];
            #pragma unroll
            for (int t = 0; t < NT; t++) {
                const int j = t * 64 + lane + 1;
                raw[t] = (valid[t] ? cost[rowbase + j - 1] : FINF) - v_[t];
            }

            float lmin = FINF;
            int   lmeta = 0x7FFFFFFF;
            #pragma unroll
            for (int t = 0; t < NT; t++) {
                if (valid[t] && !((usedbits >> t) & 1u)) {
                    const float cur = raw[t] - u0;
                    if (cur < minv_[t]) { minv_[t] = cur; way_[t] = j0; }
                    if (minv_[t] < lmin) {
                        lmin = minv_[t];
                        lmeta = ((t * 64 + lane + 1) << 5) | par_[t];
                    }
                }
            }
            const float delta = wave_min_bcast(lmin);
            const unsigned long long msk = __ballot(lmin == delta);
            const int l0 = (int)__ffsll(msk) - 1;
            const int meta = __builtin_amdgcn_readlane(lmeta, l0);
            const int j1 = meta >> 5, i1 = meta & 31;

            #pragma unroll
            for (int t = 0; t < NT; t++) {
                if ((usedbits >> t) & 1u) v_[t] -= delta;
                else                      minv_[t] -= delta;
            }

            if (i1 == 0) { j0 = j1; break; }   // free column -> augment

            // u[i1] via complementary slackness: C[i1][j1] - v[j1]
            {
                const int slot = (j1 - 1) >> 6, owner = (j1 - 1) & 63;
                float vsel = v_[0];
                #pragma unroll
                for (int t = 1; t < NT; t++) if (slot == t) vsel = v_[t];
                const float vj1 = __int_as_float(
                    __builtin_amdgcn_readlane(__float_as_int(vsel), owner));
                u0 = cost[(i1 - 1) * NQ + (j1 - 1)] - vj1;
            }
            j0 = j1; i0 = i1;
            if (++guard > 40) break;           // safety; tree <= 17 columns
        }

        // backtrack the way-chain (wave-uniform indices -> readlane)
        int jj = j0;
        while (jj) {
            const int slot = (jj - 1) >> 6, owner = (jj - 1) & 63;
            int wsel = way_[0];
            #pragma unroll
            for (int t = 1; t < NT; t++) if (slot == t) wsel = way_[t];
            const int wj = __builtin_amdgcn_readlane(wsel, owner);
            int pj;
            if (wj == 0) pj = r;
            else {
                const int s2 = (wj - 1) >> 6, o2 = (wj - 1) & 63;
                int psel = par_[0];
                #pragma unroll
                for (int t = 1; t < NT; t++) if (s2 == t) psel = par_[t];
                pj = __builtin_amdgcn_readlane(psel, o2);
            }
            #pragma unroll
            for (int t = 0; t < NT; t++)
                if (slot == t && ((jj - 1) & 63) == lane) par_[t] = pj;
            jj = wj;
        }
    }

    // ---- assigned-cost sum (exactly NG matched columns) ----
    float s = 0.f;
    #pragma unroll
    for (int t = 0; t < NT; t++) {
        const int j = t * 64 + lane + 1;
        if (valid[t] && par_[t] > 0)
            s += cost[(par_[t] - 1) * NQ + (j - 1)];
    }
    #pragma unroll
    for (int off = 32; off >= 1; off >>= 1) s += __shfl_xor(s, off);

    if (lane == 0)
        atomicAdd(out, 0.1f * (s / 4096.0f));
}

extern "C" void kernel_launch(void* const* d_in, const int* in_sizes, int n_in,
                              void* d_out, int out_size, void* d_ws, size_t ws_size,
                              hipStream_t stream) {
    (void)in_sizes; (void)n_in; (void)d_ws; (void)ws_size; (void)out_size;

    const float* pred_head    = (const float*)d_in[0];
    const float* pred_rel     = (const float*)d_in[1];
    const float* pred_tail    = (const float*)d_in[2];
    const float* IVT          = (const float*)d_in[3];
    const int*   instrumentId = (const int*)d_in[4];
    const int*   verbId       = (const int*)d_in[5];
    const int*   targetId     = (const int*)d_in[6];
    // d_in[7..9] = instrument, verb, target (unused by the reference loss)
    const int*   triplet      = (const int*)d_in[10];
    // d_in[11] = mask (all-ones in setup; all 16 gt slots valid)

    hipMemsetAsync(d_out, 0, 4, stream);   // zero the fp32 accumulator each call

    SetCriterion_14482629722575_kernel<<<256, BT, 0, stream>>>(
        pred_head, pred_rel, pred_tail, IVT,
        instrumentId, verbId, targetId, triplet, (float*)d_out);
}